// Round 4
// baseline (242.159 us; speedup 1.0000x reference)
//
#include <hip/hip_runtime.h>
#include <hip/hip_bf16.h>

#define NWIN 2048
#define LOG2E 1.44269504f
#define QSCALE 0.36067376f   // 0.25 * log2(e)

// ws layout (float offsets)
#define OFF_AFF 0        // 512 floats: [b][0..127]=softplus(scale), [128..255]=bias
#define OFF_RPB 512      // 32768 floats: rpb[h][row][l15][jt] * LOG2E  (float4-loadable)
#define OFF_WQ  33280    // 49152 bf16 (24576 floats): qkv_w packed A-frags (16x16x32)
#define OFF_WP  57856    // 16384 bf16 (8192 floats): proj_w packed B-frags (16x16x16)

typedef __attribute__((ext_vector_type(8))) __bf16 bf16x8;
typedef __attribute__((ext_vector_type(4))) float floatx4;
typedef __attribute__((ext_vector_type(4))) short short4v;

#if __has_builtin(__builtin_amdgcn_exp2f)
#define EXP2F __builtin_amdgcn_exp2f
#else
#define EXP2F exp2f
#endif

__global__ __launch_bounds__(256) void prep_kernel(
    const float* __restrict__ frame_type, const float* __restrict__ qkv_w,
    const float* __restrict__ table, const float* __restrict__ proj_w,
    const float* __restrict__ aff_w1, const float* __restrict__ aff_b1,
    const float* __restrict__ aff_w2, const int* __restrict__ rel_index,
    float* __restrict__ ws)
{
  const int gid = blockIdx.x * 256 + threadIdx.x;   // grid covers 49152
  // pack qkv_w into 16x16x32 A-frag order: idx = ((t*4+kt)*64+lane)*8+j
  // A[m=l15][k=quad*8+j] = qkv_w[t*16+l15][kt*32+quad*8+j]
  if (gid < 49152) {
    int j = gid & 7, lane = (gid >> 3) & 63, kt = (gid >> 9) & 3, t = gid >> 11;
    int n = t * 16 + (lane & 15);
    int k = kt * 32 + (lane >> 4) * 8 + j;
    ((__bf16*)(ws + OFF_WQ))[gid] = (__bf16)qkv_w[n * 128 + k];
  }
  // pack proj_w into 16x16x16 B-frag order: idx = ((h*8+nt)*64+lane)*4+j
  if (gid < 16384) {
    int j = gid & 3, lane = (gid >> 2) & 63, nt = (gid >> 8) & 7, h = gid >> 11;
    int n = nt * 16 + (lane & 15);
    int k = h * 16 + (lane >> 4) * 4 + j;
    ((__bf16*)(ws + OFF_WP))[gid] = (__bf16)proj_w[n * 128 + k];
  }
  // rpb, pre-scaled by log2(e), permuted so attn loads float4 per row:
  // dst col = l15*4 + jt  <->  src col = jt*16 + l15
  if (gid < 32768) {
    int h = gid >> 12, rem = gid & 4095, row = rem >> 6, col = rem & 63;
    int dst = h * 4096 + row * 64 + (col & 15) * 4 + (col >> 4);
    ws[OFF_RPB + dst] = table[rel_index[rem] * 8 + h] * LOG2E;
  }
  // affine params
  if (gid < 512) {
    int b = gid >> 8, c2 = gid & 255;
    float hd[16];
    #pragma unroll
    for (int j = 0; j < 16; ++j) {
      float t = frame_type[b*2+0]*aff_w1[j*2+0] + frame_type[b*2+1]*aff_w1[j*2+1] + aff_b1[j];
      hd[j] = 1.0f / (1.0f + expf(-t));
    }
    float ap = 0.f;
    #pragma unroll
    for (int j = 0; j < 16; ++j) ap += hd[j] * aff_w2[c2*16 + j];
    float r = (c2 < 128) ? ((ap > 20.f) ? ap : log1pf(expf(ap))) : ap;
    ws[OFF_AFF + gid] = r;
  }
}

__global__ __launch_bounds__(256, 4) void attn_kernel(
    const float* __restrict__ x, const float* __restrict__ mask,
    const float* __restrict__ qkv_b, const float* __restrict__ proj_b,
    const float* __restrict__ ws, float* __restrict__ out)
{
  // All buffers unpadded, XOR-swizzled on sub-blocks -> 40960 B total = 4 blocks/CU
  __shared__ __attribute__((aligned(16))) __bf16 sK [64 * 128];   // [token][d], 8B-blk ^ (token&31)
  __shared__ __attribute__((aligned(16))) __bf16 sVT[128 * 64];   // [c][token], 16B-blk ^ (c&7)
  __shared__ __attribute__((aligned(16))) __bf16 sP [4 * 16 * 64];// per-wave [ti][tj], 16B-blk ^ (ti&7)

  const int w    = blockIdx.x;
  const int b    = w >> 10;
  const int tid  = threadIdx.x;
  const int wv   = tid >> 6;
  const int lane = tid & 63;
  const int quad = lane >> 4;
  const int l15  = lane & 15;
  const int row0 = wv * 16;
  const int token = row0 + l15;

  // ---- x B-frags: ONLY our own 16 rows (M-split) ----
  bf16x8 xf[4];
  {
    const float* xw = x + (size_t)w * 8192 + (size_t)token * 128;
    #pragma unroll
    for (int kt = 0; kt < 4; ++kt) {
      const float* p = xw + kt*32 + quad*8;
      float4 f0 = *(const float4*)p;
      float4 f1 = *(const float4*)(p + 4);
      bf16x8 v;
      v[0]=(__bf16)f0.x; v[1]=(__bf16)f0.y; v[2]=(__bf16)f0.z; v[3]=(__bf16)f0.w;
      v[4]=(__bf16)f1.x; v[5]=(__bf16)f1.y; v[6]=(__bf16)f1.z; v[7]=(__bf16)f1.w;
      xf[kt] = v;
    }
  }

  const __bf16* wq = (const __bf16*)(ws + OFF_WQ);
  short4v qa[8];   // Q A-frags for 16x16x16 QK, all 8 heads, stay in registers

  // ---- Q^T: D[d=quad*4+r][token=l15]; never touches LDS ----
  #pragma unroll
  for (int t = 0; t < 8; ++t) {
    floatx4 acc = *(const floatx4*)(qkv_b + t*16 + quad*4);
    #pragma unroll
    for (int kt = 0; kt < 4; ++kt)
      acc = __builtin_amdgcn_mfma_f32_16x16x32_bf16(
          *(const bf16x8*)(wq + ((size_t)(t*4 + kt) * 64 + lane) * 8), xf[kt], acc, 0, 0, 0);
    union { short4v s; __bf16 hh[4]; } u;
    #pragma unroll
    for (int r = 0; r < 4; ++r) u.hh[r] = (__bf16)(acc[r] * QSCALE);
    qa[t] = u.s;
  }
  // ---- K^T -> sK[token][d] swizzled ----
  #pragma unroll
  for (int t = 8; t < 16; ++t) {
    floatx4 acc = *(const floatx4*)(qkv_b + t*16 + quad*4);
    #pragma unroll
    for (int kt = 0; kt < 4; ++kt)
      acc = __builtin_amdgcn_mfma_f32_16x16x32_bf16(
          *(const bf16x8*)(wq + ((size_t)(t*4 + kt) * 64 + lane) * 8), xf[kt], acc, 0, 0, 0);
    const int dblk = (t - 8) * 4 + quad;              // d>>2
    const int sw = (dblk ^ (token & 31)) * 4;
    #pragma unroll
    for (int r = 0; r < 4; ++r)
      sK[token * 128 + sw + r] = (__bf16)acc[r];
  }
  // ---- V^T -> sVT[c][token] swizzled, modulated ----
  #pragma unroll
  for (int t = 16; t < 24; ++t) {
    floatx4 acc = *(const floatx4*)(qkv_b + t*16 + quad*4);
    #pragma unroll
    for (int kt = 0; kt < 4; ++kt)
      acc = __builtin_amdgcn_mfma_f32_16x16x32_bf16(
          *(const bf16x8*)(wq + ((size_t)(t*4 + kt) * 64 + lane) * 8), xf[kt], acc, 0, 0, 0);
    const int c0 = (t - 16) * 16 + quad * 4;
    floatx4 sp = *(const floatx4*)(ws + OFF_AFF + b*256 + c0);
    floatx4 bp = *(const floatx4*)(ws + OFF_AFF + b*256 + 128 + c0);
    #pragma unroll
    for (int r = 0; r < 4; ++r) {
      const int c = c0 + r;
      const int blk = ((token >> 3) ^ (c & 7)) * 8;
      sVT[c * 64 + blk + (token & 7)] = (__bf16)fmaf(sp[r], acc[r], bp[r]);
    }
  }
  __syncthreads();   // the only barrier

  // ---- mask (hoisted, pre-scaled by log2e) + proj bias ----
  float mv[4][4];
  {
    const float* mrow = mask + (size_t)(w & 1023) * 4096;
    #pragma unroll
    for (int jt = 0; jt < 4; ++jt)
      #pragma unroll
      for (int r = 0; r < 4; ++r)
        mv[jt][r] = mrow[(row0 + quad*4 + r)*64 + jt*16 + l15] * LOG2E;
  }
  floatx4 pacc[8];
  #pragma unroll
  for (int nt = 0; nt < 8; ++nt) {
    float pb = proj_b[nt*16 + l15];
    pacc[nt] = (floatx4){pb, pb, pb, pb};
  }

  bf16x8 ones;
  #pragma unroll
  for (int i = 0; i < 8; ++i) ones[i] = (__bf16)1.0f;

  const float* rpb = ws + OFF_RPB;
  const __bf16* wp = (const __bf16*)(ws + OFF_WP);
  __bf16* sPw = sP + wv * 1024;   // wave-private 16x64

  #pragma unroll 1
  for (int h = 0; h < 8; ++h) {
    floatx4 rq[4];
    #pragma unroll
    for (int r = 0; r < 4; ++r)
      rq[r] = *(const floatx4*)(rpb + h*4096 + (row0 + quad*4 + r)*64 + l15*4);

    floatx4 s[4];
    #pragma unroll
    for (int jt = 0; jt < 4; ++jt) {
      const int tj = jt*16 + l15;
      short4v kb = *(const short4v*)(&sK[tj * 128 + ((h*4 + quad) ^ (tj & 31)) * 4]);
      floatx4 ci;
      #pragma unroll
      for (int r = 0; r < 4; ++r) ci[r] = rq[r][jt] + mv[jt][r];
      s[jt] = __builtin_amdgcn_mfma_f32_16x16x16bf16_1k(qa[h], kb, ci, 0, 0, 0);
    }
    // unnormalized probs -> sP (scores bounded, no max subtraction)
    #pragma unroll
    for (int jt = 0; jt < 4; ++jt) {
      const int cb = jt*2 + (l15 >> 3);
      #pragma unroll
      for (int r = 0; r < 4; ++r) {
        const int rl = quad*4 + r;
        sPw[rl*64 + ((cb ^ (rl & 7)) * 8) + (l15 & 7)] = (__bf16)EXP2F(s[jt][r]);
      }
    }
    // O^T = V^T * P^T ; rowsum = ones * P^T
    floatx4 o2 = {0.f,0.f,0.f,0.f}, s2 = {0.f,0.f,0.f,0.f};
    #pragma unroll
    for (int kt = 0; kt < 2; ++kt) {
      const int blk = ((kt*4 + quad) ^ (l15 & 7)) * 8;
      bf16x8 pa = *(const bf16x8*)(&sPw[l15*64 + blk]);
      bf16x8 vb = *(const bf16x8*)(&sVT[(h*16 + l15)*64 + blk]);
      o2 = __builtin_amdgcn_mfma_f32_16x16x32_bf16(vb, pa, o2, 0, 0, 0);
      s2 = __builtin_amdgcn_mfma_f32_16x16x32_bf16(ones, pa, s2, 0, 0, 0);
    }
    const float inv = 1.0f / s2[0];
    union { short4v s; __bf16 hh[4]; } u;
    #pragma unroll
    for (int r = 0; r < 4; ++r) u.hh[r] = (__bf16)(o2[r] * inv);
    #pragma unroll
    for (int nt = 0; nt < 8; ++nt) {
      short4v wpf = *(const short4v*)(wp + ((size_t)(h*8 + nt)*64 + lane)*4);
      pacc[nt] = __builtin_amdgcn_mfma_f32_16x16x16bf16_1k(u.s, wpf, pacc[nt], 0, 0, 0);
    }
  }

  // ---- store ----
  {
    float* ow = out + (size_t)w * 8192;
    #pragma unroll
    for (int nt = 0; nt < 8; ++nt)
      #pragma unroll
      for (int r = 0; r < 4; ++r)
        ow[(row0 + quad*4 + r)*128 + nt*16 + l15] = pacc[nt][r];
  }
}

extern "C" void kernel_launch(void* const* d_in, const int* in_sizes, int n_in,
                              void* d_out, int out_size, void* d_ws, size_t ws_size,
                              hipStream_t stream)
{
  const float* x          = (const float*)d_in[0];
  const float* mask       = (const float*)d_in[1];
  const float* frame_type = (const float*)d_in[2];
  const float* qkv_w      = (const float*)d_in[3];
  const float* qkv_b      = (const float*)d_in[4];
  const float* table      = (const float*)d_in[5];
  const float* proj_w     = (const float*)d_in[6];
  const float* proj_b     = (const float*)d_in[7];
  const float* aff_w1     = (const float*)d_in[8];
  const float* aff_b1     = (const float*)d_in[9];
  const float* aff_w2     = (const float*)d_in[10];
  const int*   rel_index  = (const int*)d_in[11];
  float* ws   = (float*)d_ws;
  float* outp = (float*)d_out;

  prep_kernel<<<192, 256, 0, stream>>>(frame_type, qkv_w, table, proj_w,
                                       aff_w1, aff_b1, aff_w2, rel_index, ws);
  attn_kernel<<<NWIN, 256, 0, stream>>>(x, mask, qkv_b, proj_b, ws, outp);
}